// Round 2
// baseline (996.238 us; speedup 1.0000x reference)
//
#include <hip/hip_runtime.h>
#include <math.h>

#define D1 128
#define NEG 0.2f

__device__ __forceinline__ float lrelu(float v){ return v > 0.f ? v : NEG * v; }
__device__ __forceinline__ float elu_f(float v){ return v > 0.f ? v : expm1f(v); }

// ---------------- CSR build ----------------

__global__ void k_hist(const int* __restrict__ ei, int* __restrict__ deg,
                       int n_edges, int etot){
    int e = blockIdx.x * 256 + threadIdx.x;
    if (e >= etot) return;
    int dst = (e < n_edges) ? ei[n_edges + e] : (e - n_edges);
    atomicAdd(&deg[dst], 1);
}

__global__ __launch_bounds__(1024) void k_scan1(const int* __restrict__ deg,
                                                int* __restrict__ rowptr,
                                                int* __restrict__ bsum, int n){
    __shared__ int sd[1024];
    int i = blockIdx.x * 1024 + threadIdx.x;
    int v = (i < n) ? deg[i] : 0;
    sd[threadIdx.x] = v;
    __syncthreads();
    for (int off = 1; off < 1024; off <<= 1){
        int t = (threadIdx.x >= off) ? sd[threadIdx.x - off] : 0;
        __syncthreads();
        sd[threadIdx.x] += t;
        __syncthreads();
    }
    if (i < n) rowptr[i] = sd[threadIdx.x] - v;      // exclusive scan
    if (threadIdx.x == 1023) bsum[blockIdx.x] = sd[1023];
}

__global__ void k_scan2(int* bsum, int nb){
    if (threadIdx.x == 0){
        int run = 0;
        for (int b = 0; b < nb; b++){ int t = bsum[b]; bsum[b] = run; run += t; }
    }
}

__global__ __launch_bounds__(1024) void k_scan3(int* __restrict__ rowptr,
                                                int* __restrict__ cursor,
                                                const int* __restrict__ bsum,
                                                int n, int etot){
    int i = blockIdx.x * 1024 + threadIdx.x;
    if (i < n){
        int v = rowptr[i] + bsum[blockIdx.x];
        rowptr[i] = v;
        cursor[i] = v;
    }
    if (i == 0) rowptr[n] = etot;
}

__global__ void k_scatter(const int* __restrict__ ei, int* __restrict__ cursor,
                          int* __restrict__ eidx, int n_edges, int etot){
    int e = blockIdx.x * 256 + threadIdx.x;
    if (e >= etot) return;
    int src, dst;
    if (e < n_edges){ src = ei[e]; dst = ei[n_edges + e]; }
    else            { src = dst = e - n_edges; }
    int pos = atomicAdd(&cursor[dst], 1);
    eidx[pos] = src;
}

// ---------------- weight transpose: WT[k*128+j] = W[j*128+k] ----------------

__global__ void k_transw(const float* __restrict__ W1, const float* __restrict__ W2,
                         const float* __restrict__ W3, float* __restrict__ WT){
    int t = blockIdx.x * 256 + threadIdx.x;          // 0..49151
    int w = t >> 14;
    int r = t & 16383;
    int k = r >> 7, j = r & 127;
    const float* W = (w == 0) ? W1 : (w == 1) ? W2 : W3;
    WT[t] = W[j * 128 + k];
}

// ---------------- fp32 GEMM: H[n][j] = sum_k X[n][k] * WT[k][j] ----------------
// 64 rows x 128 cols per block, 256 threads, thread = 8 rows x 4 cols

__global__ __launch_bounds__(256) void k_gemm(const float* __restrict__ X,
                                              const float* __restrict__ WT,
                                              float* __restrict__ H, int n_rows){
    __shared__ float xs[64 * 128];     // 32 KB
    __shared__ float wsm[32 * 128];    // 16 KB
    int tx = threadIdx.x & 31;         // col group: j0 = 4*tx
    int ty = threadIdx.x >> 5;         // row group: r0 = 8*ty
    int row0 = blockIdx.x * 64;

    // stage X tile (2048 float4, 8 per thread)
    #pragma unroll
    for (int i = 0; i < 8; i++){
        int idx = threadIdx.x + i * 256;
        int r = idx >> 5, c = idx & 31;
        float4 v = make_float4(0.f, 0.f, 0.f, 0.f);
        if (row0 + r < n_rows) v = ((const float4*)X)[(size_t)(row0 + r) * 32 + c];
        ((float4*)xs)[idx] = v;
    }

    float4 acc[8];
    #pragma unroll
    for (int i = 0; i < 8; i++) acc[i] = make_float4(0.f, 0.f, 0.f, 0.f);

    for (int k0 = 0; k0 < 128; k0 += 32){
        __syncthreads();
        // stage WT rows k0..k0+31 (1024 float4, 4 per thread)
        #pragma unroll
        for (int i = 0; i < 4; i++){
            int idx = threadIdx.x + i * 256;
            ((float4*)wsm)[idx] = ((const float4*)(WT + k0 * 128))[idx];
        }
        __syncthreads();
        #pragma unroll
        for (int kk = 0; kk < 32; kk++){
            float4 wv = ((float4*)wsm)[kk * 32 + tx];
            #pragma unroll
            for (int i = 0; i < 8; i++){
                float xv = xs[(ty * 8 + i) * 128 + k0 + kk];
                acc[i].x += xv * wv.x;
                acc[i].y += xv * wv.y;
                acc[i].z += xv * wv.z;
                acc[i].w += xv * wv.w;
            }
        }
    }
    #pragma unroll
    for (int i = 0; i < 8; i++){
        int r = row0 + ty * 8 + i;
        if (r < n_rows) ((float4*)H)[(size_t)r * 32 + tx] = acc[i];
    }
}

// ---------------- attention coefficients ----------------
// thread = (node, head): asrc[n][h] = dot(h[n][h*32..], a_s[h]), same for adst

__global__ void k_att(const float* __restrict__ H, const float* __restrict__ aw_s,
                      const float* __restrict__ aw_d, float* __restrict__ asrc,
                      float* __restrict__ adst, int n_nodes){
    int t = blockIdx.x * 256 + threadIdx.x;
    if (t >= n_nodes * 4) return;
    int n = t >> 2, hd = t & 3;
    const float4* hp = (const float4*)(H + (size_t)n * 128 + hd * 32);
    const float4* sp = (const float4*)(aw_s + hd * 32);
    const float4* dp = (const float4*)(aw_d + hd * 32);
    float s = 0.f, d = 0.f;
    #pragma unroll
    for (int i = 0; i < 8; i++){
        float4 h4 = hp[i], s4 = sp[i], d4 = dp[i];
        s += h4.x * s4.x + h4.y * s4.y + h4.z * s4.z + h4.w * s4.w;
        d += h4.x * d4.x + h4.y * d4.y + h4.z * d4.z + h4.w * d4.w;
    }
    asrc[t] = s;
    adst[t] = d;
}

// ---------------- softmax + aggregation, one wave per node ----------------
// lane l handles channels 2l, 2l+1 (head = l>>4). MEAN=1: layer-3 head-mean.

template<int MEAN>
__global__ __launch_bounds__(256) void k_aggr(const float* __restrict__ H,
        const float* __restrict__ asrc, const float* __restrict__ adst,
        const int* __restrict__ rowptr, const int* __restrict__ eidx,
        const float* __restrict__ bias, float* __restrict__ Out, int n_nodes){
    int lane = threadIdx.x & 63;
    int n = blockIdx.x * 4 + (threadIdx.x >> 6);
    if (n >= n_nodes) return;
    int row0 = rowptr[n];
    int deg  = rowptr[n + 1] - row0;
    float4 ad = ((const float4*)adst)[n];

    // Phase A: per-head max over incoming edges
    float m0 = -1e30f, m1 = -1e30f, m2 = -1e30f, m3 = -1e30f;
    for (int i = lane; i < deg; i += 64){
        int s = eidx[row0 + i];
        float4 av = ((const float4*)asrc)[s];
        m0 = fmaxf(m0, lrelu(av.x + ad.x));
        m1 = fmaxf(m1, lrelu(av.y + ad.y));
        m2 = fmaxf(m2, lrelu(av.z + ad.z));
        m3 = fmaxf(m3, lrelu(av.w + ad.w));
    }
    #pragma unroll
    for (int off = 32; off; off >>= 1){
        m0 = fmaxf(m0, __shfl_xor(m0, off));
        m1 = fmaxf(m1, __shfl_xor(m1, off));
        m2 = fmaxf(m2, __shfl_xor(m2, off));
        m3 = fmaxf(m3, __shfl_xor(m3, off));
    }
    // Phase B: per-head exp-sum
    float d0 = 0.f, d1 = 0.f, d2 = 0.f, d3 = 0.f;
    for (int i = lane; i < deg; i += 64){
        int s = eidx[row0 + i];
        float4 av = ((const float4*)asrc)[s];
        d0 += expf(lrelu(av.x + ad.x) - m0);
        d1 += expf(lrelu(av.y + ad.y) - m1);
        d2 += expf(lrelu(av.z + ad.z) - m2);
        d3 += expf(lrelu(av.w + ad.w) - m3);
    }
    #pragma unroll
    for (int off = 32; off; off >>= 1){
        d0 += __shfl_xor(d0, off);
        d1 += __shfl_xor(d1, off);
        d2 += __shfl_xor(d2, off);
        d3 += __shfl_xor(d3, off);
    }
    int hd = lane >> 4;
    float mh  = hd == 0 ? m0 : hd == 1 ? m1 : hd == 2 ? m2 : m3;
    float rdh = 1.f / (hd == 0 ? d0 : hd == 1 ? d1 : hd == 2 ? d2 : d3);
    float adh = hd == 0 ? ad.x : hd == 1 ? ad.y : hd == 2 ? ad.z : ad.w;

    // Phase C: weighted aggregation (4-edge ILP batching)
    float accx = 0.f, accy = 0.f;
    int c = lane * 2;
    const int* ep = eidx + row0;
    int i = 0;
    for (; i + 4 <= deg; i += 4){
        int s0 = ep[i], s1 = ep[i + 1], s2 = ep[i + 2], s3 = ep[i + 3];
        float a0 = asrc[s0 * 4 + hd], a1 = asrc[s1 * 4 + hd];
        float a2 = asrc[s2 * 4 + hd], a3 = asrc[s3 * 4 + hd];
        float2 h0 = *(const float2*)(H + (size_t)s0 * 128 + c);
        float2 h1 = *(const float2*)(H + (size_t)s1 * 128 + c);
        float2 h2 = *(const float2*)(H + (size_t)s2 * 128 + c);
        float2 h3 = *(const float2*)(H + (size_t)s3 * 128 + c);
        float w0 = expf(lrelu(a0 + adh) - mh) * rdh;
        float w1 = expf(lrelu(a1 + adh) - mh) * rdh;
        float w2 = expf(lrelu(a2 + adh) - mh) * rdh;
        float w3 = expf(lrelu(a3 + adh) - mh) * rdh;
        accx += w0 * h0.x + w1 * h1.x + w2 * h2.x + w3 * h3.x;
        accy += w0 * h0.y + w1 * h1.y + w2 * h2.y + w3 * h3.y;
    }
    for (; i < deg; i++){
        int s = ep[i];
        float w = expf(lrelu(asrc[s * 4 + hd] + adh) - mh) * rdh;
        float2 hv = *(const float2*)(H + (size_t)s * 128 + c);
        accx += w * hv.x;
        accy += w * hv.y;
    }

    if (!MEAN){
        float ox = elu_f(accx + bias[c]);
        float oy = elu_f(accy + bias[c + 1]);
        *(float2*)(Out + (size_t)n * 128 + c) = make_float2(ox, oy);
    } else {
        float sx = accx, sy = accy;
        sx += __shfl_xor(sx, 16); sy += __shfl_xor(sy, 16);
        sx += __shfl_xor(sx, 32); sy += __shfl_xor(sy, 32);
        if (lane < 16){
            int cc = lane * 2;
            float ox = elu_f(sx * 0.25f + bias[cc]);
            float oy = elu_f(sy * 0.25f + bias[cc + 1]);
            *(float2*)(Out + (size_t)n * 32 + cc) = make_float2(ox, oy);
        }
    }
}

// ---------------- readout: y = h3 @ lin_w + lin_b, mean-pool per graph ----------------

__global__ void k_readout(const float* __restrict__ H3, const int* __restrict__ batch,
                          const float* __restrict__ lw, const float* __restrict__ lb,
                          float* __restrict__ pool, float* __restrict__ cnt, int n_nodes){
    __shared__ float pl[64];
    __shared__ float cl[64];
    if (threadIdx.x < 64){ pl[threadIdx.x] = 0.f; cl[threadIdx.x] = 0.f; }
    __syncthreads();
    int n = blockIdx.x * 256 + threadIdx.x;
    if (n < n_nodes){
        const float4* hp = (const float4*)(H3 + (size_t)n * 32);
        const float4* wp = (const float4*)lw;
        float y = 0.f;
        #pragma unroll
        for (int i = 0; i < 8; i++){
            float4 h4 = hp[i], w4 = wp[i];
            y += h4.x * w4.x + h4.y * w4.y + h4.z * w4.z + h4.w * w4.w;
        }
        y += lb[0];
        int b = batch[n];
        atomicAdd(&pl[b], y);
        atomicAdd(&cl[b], 1.f);
    }
    __syncthreads();
    if (threadIdx.x < 64 && cl[threadIdx.x] != 0.f){
        atomicAdd(&pool[threadIdx.x], pl[threadIdx.x]);
        atomicAdd(&cnt[threadIdx.x], cl[threadIdx.x]);
    }
}

__global__ void k_final(const float* __restrict__ pool, const float* __restrict__ cnt,
                        float* __restrict__ out){
    int g = threadIdx.x;
    if (g < 64) out[g] = (cnt[g] > 0.f) ? pool[g] / cnt[g] : 0.f;
}

// ---------------- launch ----------------

extern "C" void kernel_launch(void* const* d_in, const int* in_sizes, int n_in,
                              void* d_out, int out_size, void* d_ws, size_t ws_size,
                              hipStream_t stream){
    const float* x   = (const float*)d_in[0];
    const int*   ei  = (const int*)  d_in[1];
    const int*   bat = (const int*)  d_in[2];
    const float* W1  = (const float*)d_in[3];
    const float* a1s = (const float*)d_in[4];
    const float* a1d = (const float*)d_in[5];
    const float* b1  = (const float*)d_in[6];
    const float* W2  = (const float*)d_in[7];
    const float* a2s = (const float*)d_in[8];
    const float* a2d = (const float*)d_in[9];
    const float* b2  = (const float*)d_in[10];
    const float* W3  = (const float*)d_in[11];
    const float* a3s = (const float*)d_in[12];
    const float* a3d = (const float*)d_in[13];
    const float* b3  = (const float*)d_in[14];
    const float* lw  = (const float*)d_in[15];
    const float* lb  = (const float*)d_in[16];
    (void)n_in; (void)out_size; (void)ws_size;

    const int n_nodes = in_sizes[0] / D1;      // 100000
    const int n_edges = in_sizes[1] / 2;       // 1600000
    const int etot    = n_edges + n_nodes;     // 1700000

    char* p = (char*)d_ws;
    size_t off = 0;
    auto alloc = [&](size_t bytes) -> char* {
        char* r = p + off;
        off = (off + bytes + 511) & ~(size_t)511;
        return r;
    };
    float* bufA   = (float*)alloc((size_t)n_nodes * D1 * 4);
    float* bufB   = (float*)alloc((size_t)n_nodes * D1 * 4);
    float* asrc   = (float*)alloc((size_t)n_nodes * 4 * 4);
    float* adst   = (float*)alloc((size_t)n_nodes * 4 * 4);
    float* WT     = (float*)alloc(3 * 128 * 128 * 4);
    int*   deg    = (int*)  alloc((size_t)n_nodes * 4);
    int*   rowptr = (int*)  alloc((size_t)(n_nodes + 1) * 4);
    int*   cursor = (int*)  alloc((size_t)n_nodes * 4);
    int*   bsum   = (int*)  alloc(4096);
    int*   eidx   = (int*)  alloc((size_t)etot * 4);
    float* pool   = (float*)alloc(64 * 4);
    float* cnt    = (float*)alloc(64 * 4);

    hipMemsetAsync(deg, 0, (size_t)n_nodes * 4, stream);
    hipMemsetAsync(pool, 0, 64 * 4, stream);
    hipMemsetAsync(cnt, 0, 64 * 4, stream);

    k_transw<<<192, 256, 0, stream>>>(W1, W2, W3, WT);

    int eb = (etot + 255) / 256;
    int nb = (n_nodes + 1023) / 1024;
    k_hist<<<eb, 256, 0, stream>>>(ei, deg, n_edges, etot);
    k_scan1<<<nb, 1024, 0, stream>>>(deg, rowptr, bsum, n_nodes);
    k_scan2<<<1, 64, 0, stream>>>(bsum, nb);
    k_scan3<<<nb, 1024, 0, stream>>>(rowptr, cursor, bsum, n_nodes, etot);
    k_scatter<<<eb, 256, 0, stream>>>(ei, cursor, eidx, n_edges, etot);

    int gb = (n_nodes + 63) / 64;
    int ab = (n_nodes * 4 + 255) / 256;
    int rb = (n_nodes + 3) / 4;

    // layer 1: x -> bufA (gemm) -> bufB (aggr)
    k_gemm<<<gb, 256, 0, stream>>>(x, WT, bufA, n_nodes);
    k_att<<<ab, 256, 0, stream>>>(bufA, a1s, a1d, asrc, adst, n_nodes);
    k_aggr<0><<<rb, 256, 0, stream>>>(bufA, asrc, adst, rowptr, eidx, b1, bufB, n_nodes);
    // layer 2: bufB -> bufA (gemm) -> bufB (aggr)
    k_gemm<<<gb, 256, 0, stream>>>(bufB, WT + 16384, bufA, n_nodes);
    k_att<<<ab, 256, 0, stream>>>(bufA, a2s, a2d, asrc, adst, n_nodes);
    k_aggr<0><<<rb, 256, 0, stream>>>(bufA, asrc, adst, rowptr, eidx, b2, bufB, n_nodes);
    // layer 3: bufB -> bufA (gemm) -> bufB (aggr, mean heads, [N][32])
    k_gemm<<<gb, 256, 0, stream>>>(bufB, WT + 32768, bufA, n_nodes);
    k_att<<<ab, 256, 0, stream>>>(bufA, a3s, a3d, asrc, adst, n_nodes);
    k_aggr<1><<<rb, 256, 0, stream>>>(bufA, asrc, adst, rowptr, eidx, b3, bufB, n_nodes);

    int ob = (n_nodes + 255) / 256;
    k_readout<<<ob, 256, 0, stream>>>(bufB, bat, lw, lb, pool, cnt, n_nodes);
    k_final<<<1, 64, 0, stream>>>(pool, cnt, (float*)d_out);
}

// Round 3
// 969.182 us; speedup vs baseline: 1.0279x; 1.0279x over previous
//
#include <hip/hip_runtime.h>
#include <math.h>

#define D1 128
#define NEG 0.2f

__device__ __forceinline__ float lrelu(float v){ return v > 0.f ? v : NEG * v; }
__device__ __forceinline__ float elu_f(float v){ return v > 0.f ? v : __expf(v) - 1.f; }

// ---------------- CSR build ----------------

__global__ void k_hist(const int* __restrict__ ei, int* __restrict__ deg,
                       int n_edges, int etot){
    int e = blockIdx.x * 256 + threadIdx.x;
    if (e >= etot) return;
    int dst = (e < n_edges) ? ei[n_edges + e] : (e - n_edges);
    atomicAdd(&deg[dst], 1);
}

__global__ __launch_bounds__(1024) void k_scan1(const int* __restrict__ deg,
                                                int* __restrict__ rowptr,
                                                int* __restrict__ bsum, int n){
    __shared__ int sd[1024];
    int i = blockIdx.x * 1024 + threadIdx.x;
    int v = (i < n) ? deg[i] : 0;
    sd[threadIdx.x] = v;
    __syncthreads();
    for (int off = 1; off < 1024; off <<= 1){
        int t = (threadIdx.x >= off) ? sd[threadIdx.x - off] : 0;
        __syncthreads();
        sd[threadIdx.x] += t;
        __syncthreads();
    }
    if (i < n) rowptr[i] = sd[threadIdx.x] - v;      // exclusive scan
    if (threadIdx.x == 1023) bsum[blockIdx.x] = sd[1023];
}

__global__ void k_scan2(int* bsum, int nb){
    if (threadIdx.x == 0){
        int run = 0;
        for (int b = 0; b < nb; b++){ int t = bsum[b]; bsum[b] = run; run += t; }
    }
}

__global__ __launch_bounds__(1024) void k_scan3(int* __restrict__ rowptr,
                                                int* __restrict__ cursor,
                                                const int* __restrict__ bsum,
                                                int n, int etot){
    int i = blockIdx.x * 1024 + threadIdx.x;
    if (i < n){
        int v = rowptr[i] + bsum[blockIdx.x];
        rowptr[i] = v;
        cursor[i] = v;
    }
    if (i == 0) rowptr[n] = etot;
}

__global__ void k_scatter(const int* __restrict__ ei, int* __restrict__ cursor,
                          int* __restrict__ eidx, int n_edges, int etot){
    int e = blockIdx.x * 256 + threadIdx.x;
    if (e >= etot) return;
    int src, dst;
    if (e < n_edges){ src = ei[e]; dst = ei[n_edges + e]; }
    else            { src = dst = e - n_edges; }
    int pos = atomicAdd(&cursor[dst], 1);
    eidx[pos] = src;
}

// ---------------- weight transpose: WT[k*128+j] = W[j*128+k] ----------------

__global__ void k_transw(const float* __restrict__ W1, const float* __restrict__ W2,
                         const float* __restrict__ W3, float* __restrict__ WT){
    int t = blockIdx.x * 256 + threadIdx.x;          // 0..49151
    int w = t >> 14;
    int r = t & 16383;
    int k = r >> 7, j = r & 127;
    const float* W = (w == 0) ? W1 : (w == 1) ? W2 : W3;
    WT[t] = W[j * 128 + k];
}

// ---------------- fp32 GEMM: H[n][j] = sum_k X[n][k] * WT[k][j] ----------------

__global__ __launch_bounds__(256) void k_gemm(const float* __restrict__ X,
                                              const float* __restrict__ WT,
                                              float* __restrict__ H, int n_rows){
    __shared__ float xs[64 * 128];     // 32 KB
    __shared__ float wsm[32 * 128];    // 16 KB
    int tx = threadIdx.x & 31;         // col group: j0 = 4*tx
    int ty = threadIdx.x >> 5;         // row group: r0 = 8*ty
    int row0 = blockIdx.x * 64;

    #pragma unroll
    for (int i = 0; i < 8; i++){
        int idx = threadIdx.x + i * 256;
        int r = idx >> 5, c = idx & 31;
        float4 v = make_float4(0.f, 0.f, 0.f, 0.f);
        if (row0 + r < n_rows) v = ((const float4*)X)[(size_t)(row0 + r) * 32 + c];
        ((float4*)xs)[idx] = v;
    }

    float4 acc[8];
    #pragma unroll
    for (int i = 0; i < 8; i++) acc[i] = make_float4(0.f, 0.f, 0.f, 0.f);

    for (int k0 = 0; k0 < 128; k0 += 32){
        __syncthreads();
        #pragma unroll
        for (int i = 0; i < 4; i++){
            int idx = threadIdx.x + i * 256;
            ((float4*)wsm)[idx] = ((const float4*)(WT + k0 * 128))[idx];
        }
        __syncthreads();
        #pragma unroll
        for (int kk = 0; kk < 32; kk++){
            float4 wv = ((float4*)wsm)[kk * 32 + tx];
            #pragma unroll
            for (int i = 0; i < 8; i++){
                float xv = xs[(ty * 8 + i) * 128 + k0 + kk];
                acc[i].x += xv * wv.x;
                acc[i].y += xv * wv.y;
                acc[i].z += xv * wv.z;
                acc[i].w += xv * wv.w;
            }
        }
    }
    #pragma unroll
    for (int i = 0; i < 8; i++){
        int r = row0 + ty * 8 + i;
        if (r < n_rows) ((float4*)H)[(size_t)r * 32 + tx] = acc[i];
    }
}

// ---------------- attention coefficients ----------------

__global__ void k_att(const float* __restrict__ H, const float* __restrict__ aw_s,
                      const float* __restrict__ aw_d, float* __restrict__ asrc,
                      float* __restrict__ adst, int n_nodes){
    int t = blockIdx.x * 256 + threadIdx.x;
    if (t >= n_nodes * 4) return;
    int n = t >> 2, hd = t & 3;
    const float4* hp = (const float4*)(H + (size_t)n * 128 + hd * 32);
    const float4* sp = (const float4*)(aw_s + hd * 32);
    const float4* dp = (const float4*)(aw_d + hd * 32);
    float s = 0.f, d = 0.f;
    #pragma unroll
    for (int i = 0; i < 8; i++){
        float4 h4 = hp[i], s4 = sp[i], d4 = dp[i];
        s += h4.x * s4.x + h4.y * s4.y + h4.z * s4.z + h4.w * s4.w;
        d += h4.x * d4.x + h4.y * d4.y + h4.z * d4.z + h4.w * d4.w;
    }
    asrc[t] = s;
    adst[t] = d;
}

// ---------------- softmax + aggregation, one wave per node ----------------
// Phase A+B fused (reg-cached first 64 edges), unnormalized exp stored in LDS
// (wave-private, no barrier), phase C = ds_read + gather + 2 FMA per edge,
// 1/denom factored out of the sum. CAP=96 with recompute fallback (deg>96
// is astronomically rare for Poisson(17) but must stay correct).

#define AGGR_CAP 96

template<int MEAN>
__global__ __launch_bounds__(256) void k_aggr(const float* __restrict__ H,
        const float* __restrict__ asrc, const float* __restrict__ adst,
        const int* __restrict__ rowptr, const int* __restrict__ eidx,
        const float* __restrict__ bias, float* __restrict__ Out, int n_nodes){
    __shared__ float wls[4][AGGR_CAP * 4];     // 6 KB
    int lane = threadIdx.x & 63;
    int wid  = threadIdx.x >> 6;
    int n = blockIdx.x * 4 + wid;
    if (n >= n_nodes) return;
    int row0 = rowptr[n];
    int deg  = rowptr[n + 1] - row0;
    float4 ad = ((const float4*)adst)[n];
    float* wl = wls[wid];
    const int* ep = eidx + row0;

    // Phase A: edge scores (first strided round cached in regs) + max
    float e0 = -1e30f, e1 = -1e30f, e2 = -1e30f, e3 = -1e30f;
    if (lane < deg){
        int s = ep[lane];
        float4 av = ((const float4*)asrc)[s];
        e0 = lrelu(av.x + ad.x); e1 = lrelu(av.y + ad.y);
        e2 = lrelu(av.z + ad.z); e3 = lrelu(av.w + ad.w);
    }
    float m0 = e0, m1 = e1, m2 = e2, m3 = e3;
    for (int i = lane + 64; i < deg; i += 64){   // rare (deg > 64)
        int s = ep[i];
        float4 av = ((const float4*)asrc)[s];
        m0 = fmaxf(m0, lrelu(av.x + ad.x));
        m1 = fmaxf(m1, lrelu(av.y + ad.y));
        m2 = fmaxf(m2, lrelu(av.z + ad.z));
        m3 = fmaxf(m3, lrelu(av.w + ad.w));
    }
    #pragma unroll
    for (int off = 32; off; off >>= 1){
        m0 = fmaxf(m0, __shfl_xor(m0, off));
        m1 = fmaxf(m1, __shfl_xor(m1, off));
        m2 = fmaxf(m2, __shfl_xor(m2, off));
        m3 = fmaxf(m3, __shfl_xor(m3, off));
    }

    // Phase B: unnormalized exp -> LDS, accumulate denom
    float d0 = 0.f, d1 = 0.f, d2 = 0.f, d3 = 0.f;
    if (lane < deg){
        float x0 = __expf(e0 - m0), x1 = __expf(e1 - m1);
        float x2 = __expf(e2 - m2), x3 = __expf(e3 - m3);
        d0 = x0; d1 = x1; d2 = x2; d3 = x3;
        ((float4*)wl)[lane] = make_float4(x0, x1, x2, x3);
    }
    for (int i = lane + 64; i < deg; i += 64){   // rare
        int s = ep[i];
        float4 av = ((const float4*)asrc)[s];
        float x0 = __expf(lrelu(av.x + ad.x) - m0);
        float x1 = __expf(lrelu(av.y + ad.y) - m1);
        float x2 = __expf(lrelu(av.z + ad.z) - m2);
        float x3 = __expf(lrelu(av.w + ad.w) - m3);
        d0 += x0; d1 += x1; d2 += x2; d3 += x3;
        if (i < AGGR_CAP) ((float4*)wl)[i] = make_float4(x0, x1, x2, x3);
    }
    #pragma unroll
    for (int off = 32; off; off >>= 1){
        d0 += __shfl_xor(d0, off);
        d1 += __shfl_xor(d1, off);
        d2 += __shfl_xor(d2, off);
        d3 += __shfl_xor(d3, off);
    }
    int hd = lane >> 4;
    float mh  = hd == 0 ? m0 : hd == 1 ? m1 : hd == 2 ? m2 : m3;
    float rdh = 1.f / (hd == 0 ? d0 : hd == 1 ? d1 : hd == 2 ? d2 : d3);
    float adh = hd == 0 ? ad.x : hd == 1 ? ad.y : hd == 2 ? ad.z : ad.w;

    // Phase C: acc = sum_e w_e * h_e ; normalize once at the end
    float accx = 0.f, accy = 0.f;
    int c = lane * 2;
    const float* wlh = wl + hd;
    int cap = deg < AGGR_CAP ? deg : AGGR_CAP;
    int i = 0;
    for (; i + 4 <= cap; i += 4){
        int s0 = ep[i], s1 = ep[i + 1], s2 = ep[i + 2], s3 = ep[i + 3];
        float w0 = wlh[i * 4], w1 = wlh[i * 4 + 4];
        float w2 = wlh[i * 4 + 8], w3 = wlh[i * 4 + 12];
        float2 h0 = *(const float2*)(H + (size_t)s0 * 128 + c);
        float2 h1 = *(const float2*)(H + (size_t)s1 * 128 + c);
        float2 h2 = *(const float2*)(H + (size_t)s2 * 128 + c);
        float2 h3 = *(const float2*)(H + (size_t)s3 * 128 + c);
        accx += w0 * h0.x + w1 * h1.x + w2 * h2.x + w3 * h3.x;
        accy += w0 * h0.y + w1 * h1.y + w2 * h2.y + w3 * h3.y;
    }
    for (; i < cap; i++){
        int s = ep[i];
        float w = wlh[i * 4];
        float2 hv = *(const float2*)(H + (size_t)s * 128 + c);
        accx += w * hv.x;
        accy += w * hv.y;
    }
    for (; i < deg; i++){                        // deg > CAP fallback
        int s = ep[i];
        float w = __expf(lrelu(asrc[s * 4 + hd] + adh) - mh);
        float2 hv = *(const float2*)(H + (size_t)s * 128 + c);
        accx += w * hv.x;
        accy += w * hv.y;
    }
    accx *= rdh; accy *= rdh;

    if (!MEAN){
        float ox = elu_f(accx + bias[c]);
        float oy = elu_f(accy + bias[c + 1]);
        *(float2*)(Out + (size_t)n * 128 + c) = make_float2(ox, oy);
    } else {
        float sx = accx, sy = accy;
        sx += __shfl_xor(sx, 16); sy += __shfl_xor(sy, 16);
        sx += __shfl_xor(sx, 32); sy += __shfl_xor(sy, 32);
        if (lane < 16){
            int cc = lane * 2;
            float ox = elu_f(sx * 0.25f + bias[cc]);
            float oy = elu_f(sy * 0.25f + bias[cc + 1]);
            *(float2*)(Out + (size_t)n * 32 + cc) = make_float2(ox, oy);
        }
    }
}

// ---------------- readout ----------------

__global__ void k_readout(const float* __restrict__ H3, const int* __restrict__ batch,
                          const float* __restrict__ lw, const float* __restrict__ lb,
                          float* __restrict__ pool, float* __restrict__ cnt, int n_nodes){
    __shared__ float pl[64];
    __shared__ float cl[64];
    if (threadIdx.x < 64){ pl[threadIdx.x] = 0.f; cl[threadIdx.x] = 0.f; }
    __syncthreads();
    int n = blockIdx.x * 256 + threadIdx.x;
    if (n < n_nodes){
        const float4* hp = (const float4*)(H3 + (size_t)n * 32);
        const float4* wp = (const float4*)lw;
        float y = 0.f;
        #pragma unroll
        for (int i = 0; i < 8; i++){
            float4 h4 = hp[i], w4 = wp[i];
            y += h4.x * w4.x + h4.y * w4.y + h4.z * w4.z + h4.w * w4.w;
        }
        y += lb[0];
        int b = batch[n];
        atomicAdd(&pl[b], y);
        atomicAdd(&cl[b], 1.f);
    }
    __syncthreads();
    if (threadIdx.x < 64 && cl[threadIdx.x] != 0.f){
        atomicAdd(&pool[threadIdx.x], pl[threadIdx.x]);
        atomicAdd(&cnt[threadIdx.x], cl[threadIdx.x]);
    }
}

__global__ void k_final(const float* __restrict__ pool, const float* __restrict__ cnt,
                        float* __restrict__ out){
    int g = threadIdx.x;
    if (g < 64) out[g] = (cnt[g] > 0.f) ? pool[g] / cnt[g] : 0.f;
}

// ---------------- launch ----------------

extern "C" void kernel_launch(void* const* d_in, const int* in_sizes, int n_in,
                              void* d_out, int out_size, void* d_ws, size_t ws_size,
                              hipStream_t stream){
    const float* x   = (const float*)d_in[0];
    const int*   ei  = (const int*)  d_in[1];
    const int*   bat = (const int*)  d_in[2];
    const float* W1  = (const float*)d_in[3];
    const float* a1s = (const float*)d_in[4];
    const float* a1d = (const float*)d_in[5];
    const float* b1  = (const float*)d_in[6];
    const float* W2  = (const float*)d_in[7];
    const float* a2s = (const float*)d_in[8];
    const float* a2d = (const float*)d_in[9];
    const float* b2  = (const float*)d_in[10];
    const float* W3  = (const float*)d_in[11];
    const float* a3s = (const float*)d_in[12];
    const float* a3d = (const float*)d_in[13];
    const float* b3  = (const float*)d_in[14];
    const float* lw  = (const float*)d_in[15];
    const float* lb  = (const float*)d_in[16];
    (void)n_in; (void)out_size; (void)ws_size;

    const int n_nodes = in_sizes[0] / D1;      // 100000
    const int n_edges = in_sizes[1] / 2;       // 1600000
    const int etot    = n_edges + n_nodes;     // 1700000

    char* p = (char*)d_ws;
    size_t off = 0;
    auto alloc = [&](size_t bytes) -> char* {
        char* r = p + off;
        off = (off + bytes + 511) & ~(size_t)511;
        return r;
    };
    float* bufA   = (float*)alloc((size_t)n_nodes * D1 * 4);
    float* bufB   = (float*)alloc((size_t)n_nodes * D1 * 4);
    float* asrc   = (float*)alloc((size_t)n_nodes * 4 * 4);
    float* adst   = (float*)alloc((size_t)n_nodes * 4 * 4);
    float* WT     = (float*)alloc(3 * 128 * 128 * 4);
    int*   deg    = (int*)  alloc((size_t)n_nodes * 4);
    int*   rowptr = (int*)  alloc((size_t)(n_nodes + 1) * 4);
    int*   cursor = (int*)  alloc((size_t)n_nodes * 4);
    int*   bsum   = (int*)  alloc(4096);
    int*   eidx   = (int*)  alloc((size_t)etot * 4);
    float* pool   = (float*)alloc(64 * 4);
    float* cnt    = (float*)alloc(64 * 4);

    hipMemsetAsync(deg, 0, (size_t)n_nodes * 4, stream);
    hipMemsetAsync(pool, 0, 64 * 4, stream);
    hipMemsetAsync(cnt, 0, 64 * 4, stream);

    k_transw<<<192, 256, 0, stream>>>(W1, W2, W3, WT);

    int eb = (etot + 255) / 256;
    int nb = (n_nodes + 1023) / 1024;
    k_hist<<<eb, 256, 0, stream>>>(ei, deg, n_edges, etot);
    k_scan1<<<nb, 1024, 0, stream>>>(deg, rowptr, bsum, n_nodes);
    k_scan2<<<1, 64, 0, stream>>>(bsum, nb);
    k_scan3<<<nb, 1024, 0, stream>>>(rowptr, cursor, bsum, n_nodes, etot);
    k_scatter<<<eb, 256, 0, stream>>>(ei, cursor, eidx, n_edges, etot);

    int gb = (n_nodes + 63) / 64;
    int ab = (n_nodes * 4 + 255) / 256;
    int rb = (n_nodes + 3) / 4;

    // layer 1
    k_gemm<<<gb, 256, 0, stream>>>(x, WT, bufA, n_nodes);
    k_att<<<ab, 256, 0, stream>>>(bufA, a1s, a1d, asrc, adst, n_nodes);
    k_aggr<0><<<rb, 256, 0, stream>>>(bufA, asrc, adst, rowptr, eidx, b1, bufB, n_nodes);
    // layer 2
    k_gemm<<<gb, 256, 0, stream>>>(bufB, WT + 16384, bufA, n_nodes);
    k_att<<<ab, 256, 0, stream>>>(bufA, a2s, a2d, asrc, adst, n_nodes);
    k_aggr<0><<<rb, 256, 0, stream>>>(bufA, asrc, adst, rowptr, eidx, b2, bufB, n_nodes);
    // layer 3
    k_gemm<<<gb, 256, 0, stream>>>(bufB, WT + 32768, bufA, n_nodes);
    k_att<<<ab, 256, 0, stream>>>(bufA, a3s, a3d, asrc, adst, n_nodes);
    k_aggr<1><<<rb, 256, 0, stream>>>(bufA, asrc, adst, rowptr, eidx, b3, bufB, n_nodes);

    int ob = (n_nodes + 255) / 256;
    k_readout<<<ob, 256, 0, stream>>>(bufB, bat, lw, lb, pool, cnt, n_nodes);
    k_final<<<1, 64, 0, stream>>>(pool, cnt, (float*)d_out);
}